// Round 5
// baseline (905.406 us; speedup 1.0000x reference)
//
#include <hip/hip_runtime.h>

// VectorQuantizer: N=262144 rows, D=64 dims, K=512 codewords, fp32.
// out layout (floats): [0,N) idx ; [N, N+N*D) quantized_st ; [N+N*D] vq_loss
//
// CORRECTNESS MODEL (verified R2-R4, absmax 0): reference's fp32 bit pattern is
//   d2 = fl(fl(x2 - fl(2*m)) + w2), x2/w2 numpy pairwise-8 order, m = sequential
//   FMA chain d ascending (BLAS), argmin strict < (first-min tie-break).
// R5: two-phase. Phase-1 MFMA (bf16 hi/mid truncated splits of -2w, 3 product
// terms, 6 chained mfma_16x16x32_bf16 per tile) scores every (row,cw) to
// ~1.5e-4 worst-case; rows whose top-2 separation < MARG get the bit-exact
// fp32 chain re-run in a recheck kernel. Unflagged winners provably match.
#define NROWS 262144
#define DDIM  64
#define KCB   512

// phase-1 key: (fp32 bits of s''=w2+3-2*dot) << 9 | cw. s'' in [2.6,3.4] => one
// exponent octave [2,4) => bits monotone. 1 bit-unit = ulp(3)=2.38e-7.
// MARGKEY = 3<<18 => margin 1536 ulps = 3.66e-4 (>=2.3x worst-case err bound).
#define MARGKEY (3u << 18)

// ws layout (bytes): [0]=cnt, [64]=w2 f32[512], [2112]=w2p3 f32[512],
// [4160]=whi u16[512*64], [69696]=wmid u16[512*64], [135232...]=flag list
#define WS_CNT   0
#define WS_W2    64
#define WS_W2P3  2112
#define WS_WHI   4160
#define WS_WMID  69696
#define WS_LIST  135232

typedef __attribute__((ext_vector_type(8))) short short8;
typedef __attribute__((ext_vector_type(4))) float floatx4;

__device__ __forceinline__ unsigned umin2(unsigned a, unsigned b) { return a < b ? a : b; }
__device__ __forceinline__ unsigned umax2(unsigned a, unsigned b) { return a > b ? a : b; }

// numpy FLOAT_pairwise_sum order for n=64 over terms fl(a[i]*a[i])  [R2-verified]
__device__ __forceinline__ float np_sumsq64(const float* a) {
    float r[8];
#pragma unroll
    for (int j = 0; j < 8; ++j) r[j] = __fmul_rn(a[j], a[j]);
#pragma unroll
    for (int i = 8; i < 64; i += 8) {
#pragma unroll
        for (int j = 0; j < 8; ++j)
            r[j] = __fadd_rn(r[j], __fmul_rn(a[i + j], a[i + j]));
    }
    return __fadd_rn(__fadd_rn(__fadd_rn(r[0], r[1]), __fadd_rn(r[2], r[3])),
                     __fadd_rn(__fadd_rn(r[4], r[5]), __fadd_rn(r[6], r[7])));
}

// ---- prep: w2 (exact), w2p3 = w2+3, bf16 truncated splits of v = -2*w ----
__global__ void vq_prep(const float* __restrict__ w, float* __restrict__ w2,
                        float* __restrict__ w2p3, unsigned short* __restrict__ whi,
                        unsigned short* __restrict__ wmid) {
    const int k = threadIdx.x;  // 512 threads, 1 block
    float ws[64];
    const float4* wp = (const float4*)(w + (size_t)k * DDIM);
#pragma unroll
    for (int j = 0; j < 16; ++j) {
        float4 v = wp[j];
        ws[4 * j + 0] = v.x; ws[4 * j + 1] = v.y;
        ws[4 * j + 2] = v.z; ws[4 * j + 3] = v.w;
    }
    float s = np_sumsq64(ws);
    w2[k] = s;
    w2p3[k] = __fadd_rn(s, 3.0f);
#pragma unroll
    for (int d = 0; d < 64; ++d) {
        float v = __fmul_rn(-2.0f, ws[d]);          // exact (pow2 scale)
        unsigned u = __float_as_uint(v);
        whi[k * 64 + d] = (unsigned short)(u >> 16); // bf16 truncate
        float hi = __uint_as_float(u & 0xFFFF0000u);
        float rem = __fsub_rn(v, hi);                // exact
        wmid[k * 64 + d] = (unsigned short)(__float_as_uint(rem) >> 16);
    }
}

// pack two fp32 into one dword of bf16 (truncated) hi-parts + build mid dword
__device__ __forceinline__ void split2(float e0, float e1, unsigned& hid, unsigned& mid) {
    unsigned u0 = __float_as_uint(e0), u1 = __float_as_uint(e1);
    float r0 = __fsub_rn(e0, __uint_as_float(u0 & 0xFFFF0000u));  // exact
    float r1 = __fsub_rn(e1, __uint_as_float(u1 & 0xFFFF0000u));  // exact
    hid = (u0 >> 16) | (u1 & 0xFFFF0000u);
    mid = (__float_as_uint(r0) >> 16) | (__float_as_uint(r1) & 0xFFFF0000u);
}

// ---- phase-1 GEMM+argmin: 512 thr = 8 waves; wave owns 64 codewords (A-regs),
// 16 rows stream per iteration as B-frags converted in-reg ----
__launch_bounds__(512, 4)
__global__ void vq_gemm(const float* __restrict__ x,
                        const unsigned short* __restrict__ whi,
                        const unsigned short* __restrict__ wmid,
                        const float* __restrict__ w2p3g,
                        float* __restrict__ out_idx,
                        unsigned* __restrict__ cnt,
                        unsigned* __restrict__ list, int listcap) {
    const int tid = threadIdx.x;
    const int wave = tid >> 6, lane = tid & 63;
    const int n16 = lane & 15, quad = lane >> 4;

    __shared__ float w2p3s[KCB];
    __shared__ uint2 red[2][8][16];
    w2p3s[tid] = w2p3g[tid];

    // A-frags: w splits for this wave's 64 codewords. A[m=lane&15][k=quad*8+j]
    short8 ah[4][2], am[4][2];
#pragma unroll
    for (int f = 0; f < 4; ++f) {
        const int cw = wave * 64 + f * 16 + n16;
#pragma unroll
        for (int s = 0; s < 2; ++s) {
            ah[f][s] = *(const short8*)(whi + (size_t)cw * 64 + s * 32 + quad * 8);
            am[f][s] = *(const short8*)(wmid + (size_t)cw * 64 + s * 32 + quad * 8);
        }
    }
    const int cwq = wave * 64 + quad * 4;
    __syncthreads();

    for (int it = 0; it < 32; ++it) {
        const int r0 = blockIdx.x * 512 + it * 16;
        // B-frags: x row (r0+n16), d = s*32 + quad*8 + j  (fp32 -> hi/mid bf16)
        const float* xr = x + (size_t)(r0 + n16) * DDIM + quad * 8;
        float4 f0 = *(const float4*)(xr);
        float4 f1 = *(const float4*)(xr + 4);
        float4 f2 = *(const float4*)(xr + 32);
        float4 f3 = *(const float4*)(xr + 36);
        union { short8 v; unsigned u[4]; } bh0, bm0, bh1, bm1;
        split2(f0.x, f0.y, bh0.u[0], bm0.u[0]);
        split2(f0.z, f0.w, bh0.u[1], bm0.u[1]);
        split2(f1.x, f1.y, bh0.u[2], bm0.u[2]);
        split2(f1.z, f1.w, bh0.u[3], bm0.u[3]);
        split2(f2.x, f2.y, bh1.u[0], bm1.u[0]);
        split2(f2.z, f2.w, bh1.u[1], bm1.u[1]);
        split2(f3.x, f3.y, bh1.u[2], bm1.u[2]);
        split2(f3.z, f3.w, bh1.u[3], bm1.u[3]);

        // acc init = w2+3 for cw = cwq + f*16 + reg, then 6 chained MFMAs:
        // acc = (w2+3) + (-2w_hi)x_hi + (-2w_hi)x_mid + (-2w_mid)x_hi  (2 K-steps)
        floatx4 acc[4];
#pragma unroll
        for (int f = 0; f < 4; ++f)
            acc[f] = *(const floatx4*)&w2p3s[wave * 64 + f * 16 + quad * 4];
#pragma unroll
        for (int f = 0; f < 4; ++f) {
            acc[f] = __builtin_amdgcn_mfma_f32_16x16x32_bf16(ah[f][0], bh0.v, acc[f], 0, 0, 0);
            acc[f] = __builtin_amdgcn_mfma_f32_16x16x32_bf16(ah[f][0], bm0.v, acc[f], 0, 0, 0);
            acc[f] = __builtin_amdgcn_mfma_f32_16x16x32_bf16(am[f][0], bh0.v, acc[f], 0, 0, 0);
            acc[f] = __builtin_amdgcn_mfma_f32_16x16x32_bf16(ah[f][1], bh1.v, acc[f], 0, 0, 0);
            acc[f] = __builtin_amdgcn_mfma_f32_16x16x32_bf16(ah[f][1], bm1.v, acc[f], 0, 0, 0);
            acc[f] = __builtin_amdgcn_mfma_f32_16x16x32_bf16(am[f][1], bh1.v, acc[f], 0, 0, 0);
        }

        // per-lane min1/min2 over 16 scores (this lane's cw set, row r0+n16)
        unsigned m1 = 0xFFFFFFFFu, m2 = 0xFFFFFFFFu;
#pragma unroll
        for (int f = 0; f < 4; ++f) {
#pragma unroll
            for (int reg = 0; reg < 4; ++reg) {
                unsigned key = (__float_as_uint(acc[f][reg]) << 9) +
                               (unsigned)(cwq + f * 16 + reg);
                unsigned t = umax2(m1, key);
                m2 = umin2(m2, t);
                m1 = umin2(m1, key);
            }
        }
        // merge across the 4 quads holding the same row
#pragma unroll
        for (int s = 16; s <= 32; s <<= 1) {
            unsigned o1 = __shfl_xor((int)m1, s);
            unsigned o2 = __shfl_xor((int)m2, s);
            m2 = umin2(umin2(m2, o2), umax2(m1, o1));
            m1 = umin2(m1, o1);
        }
        if (lane < 16) red[it & 1][wave][n16] = make_uint2(m1, m2);
        __syncthreads();
        if (tid < 16) {  // wave 0: merge 8 waves per row, emit idx + flag
            unsigned a1 = 0xFFFFFFFFu, a2 = 0xFFFFFFFFu;
#pragma unroll
            for (int wv = 0; wv < 8; ++wv) {
                uint2 v = red[it & 1][wv][tid];
                a2 = umin2(umin2(a2, v.y), umax2(a1, v.x));
                a1 = umin2(a1, v.x);
            }
            const int row = r0 + tid;
            out_idx[row] = (float)(a1 & 511u);
            if (a2 - a1 < MARGKEY) {
                unsigned pos = atomicAdd(cnt, 1u);
                if ((int)pos < listcap) list[pos] = (unsigned)row;
            }
        }
        // no 2nd barrier: red is double-buffered; next write targets buf^1 and
        // the next iteration's barrier orders wave0's reads vs buf reuse.
    }
}

// ---- recheck: bit-exact fp32 chain for flagged rows (one wave per row) ----
__global__ void vq_recheck(const float* __restrict__ x, const float* __restrict__ w,
                           const float* __restrict__ w2,
                           const unsigned* __restrict__ cnt,
                           const unsigned* __restrict__ list, int listcap,
                           float* __restrict__ out_idx) {
    unsigned total = *cnt;
    if (total > (unsigned)listcap) total = (unsigned)listcap;
    const int lane = threadIdx.x & 63;
    const unsigned gw = blockIdx.x * (blockDim.x >> 6) + (threadIdx.x >> 6);
    const unsigned stride = gridDim.x * (blockDim.x >> 6);

    for (unsigned i = gw; i < total; i += stride) {
        const int row = (int)list[i];
        const float* xr = x + (size_t)row * DDIM;
        // x2 in numpy pairwise-8 order (R2-verified); loads L1-hot
        float r[8];
#pragma unroll
        for (int j = 0; j < 8; ++j) { float a = xr[j]; r[j] = __fmul_rn(a, a); }
#pragma unroll
        for (int ii = 8; ii < 64; ii += 8) {
#pragma unroll
            for (int j = 0; j < 8; ++j) {
                float a = xr[ii + j];
                r[j] = __fadd_rn(r[j], __fmul_rn(a, a));
            }
        }
        float x2 = __fadd_rn(__fadd_rn(__fadd_rn(r[0], r[1]), __fadd_rn(r[2], r[3])),
                             __fadd_rn(__fadd_rn(r[4], r[5]), __fadd_rn(r[6], r[7])));

        float best = 3.4e38f;
        int bidx = 0x7FFFFFFF;
#pragma unroll
        for (int jj = 0; jj < 8; ++jj) {
            const int c = lane + 64 * jj;   // ascending per lane
            const float* wr = w + (size_t)c * DDIM;
            float m = 0.0f;
#pragma unroll
            for (int d = 0; d < 64; ++d) m = __fmaf_rn(xr[d], wr[d], m);
            float q = __fadd_rn(__fsub_rn(x2, __fmul_rn(2.0f, m)), w2[c]);
            if (q < best) { best = q; bidx = c; }  // strict < keeps lowest c
        }
#pragma unroll
        for (int s = 1; s < 64; s <<= 1) {
            float ov = __shfl_xor(best, s);
            int   oi = __shfl_xor(bidx, s);
            if (ov < best || (ov == best && oi < bidx)) { best = ov; bidx = oi; }
        }
        if (lane == 0) out_idx[row] = (float)bidx;
    }
}

// ---- epilogue: gather codeword, quantized_st = fl(x + fl(q-x)), loss [R4-verified] ----
__launch_bounds__(256)
__global__ void vq_epilogue(const float* __restrict__ x,
                            const float* __restrict__ w,
                            const float* __restrict__ out_idx_f,
                            float* __restrict__ out_q,
                            float* __restrict__ out_loss) {
    const int row  = blockIdx.x * blockDim.x + threadIdx.x;
    const int bidx = (int)out_idx_f[row];

    const float4* xp = (const float4*)(x + (size_t)row * DDIM);
    const float4* wq = (const float4*)(w + (size_t)bidx * DDIM);
    float4* qo = (float4*)(out_q + (size_t)row * DDIM);
    float ls = 0.0f;
#pragma unroll
    for (int j = 0; j < 16; ++j) {
        float4 xv = xp[j];
        float4 wv = wq[j];
        float e0 = __fsub_rn(wv.x, xv.x), e1 = __fsub_rn(wv.y, xv.y);
        float e2 = __fsub_rn(wv.z, xv.z), e3 = __fsub_rn(wv.w, xv.w);
        ls = fmaf(e0, e0, ls); ls = fmaf(e1, e1, ls);
        ls = fmaf(e2, e2, ls); ls = fmaf(e3, e3, ls);
        float4 q;
        q.x = __fadd_rn(xv.x, e0); q.y = __fadd_rn(xv.y, e1);
        q.z = __fadd_rn(xv.z, e2); q.w = __fadd_rn(xv.w, e3);
        qo[j] = q;
    }
#pragma unroll
    for (int off = 32; off > 0; off >>= 1) ls += __shfl_down(ls, off);
    __shared__ float red[4];
    const int lane = threadIdx.x & 63;
    const int wid  = threadIdx.x >> 6;
    if (lane == 0) red[wid] = ls;
    __syncthreads();
    if (threadIdx.x == 0) {
        float t = (red[0] + red[1]) + (red[2] + red[3]);
        atomicAdd(out_loss, t * (1.25f / (float)(NROWS * DDIM)));  // (1+BETA)*mean
    }
}

extern "C" void kernel_launch(void* const* d_in, const int* in_sizes, int n_in,
                              void* d_out, int out_size, void* d_ws, size_t ws_size,
                              hipStream_t stream) {
    const float* x = (const float*)d_in[0];   // encoding [N, 64]
    const float* w = (const float*)d_in[1];   // weight   [512, 64]

    float* out      = (float*)d_out;
    float* out_idx  = out;
    float* out_q    = out + (size_t)NROWS;
    float* out_loss = out + (size_t)NROWS + (size_t)NROWS * DDIM;

    char* ws = (char*)d_ws;
    unsigned* cnt  = (unsigned*)(ws + WS_CNT);
    float* w2      = (float*)(ws + WS_W2);
    float* w2p3    = (float*)(ws + WS_W2P3);
    unsigned short* whi  = (unsigned short*)(ws + WS_WHI);
    unsigned short* wmid = (unsigned short*)(ws + WS_WMID);
    unsigned* list = (unsigned*)(ws + WS_LIST);
    long cap = ((long)ws_size - WS_LIST) / 4;
    int listcap = cap > 0 ? (cap > NROWS ? NROWS : (int)cap) : 0;

    hipMemsetAsync(out_loss, 0, sizeof(float), stream);
    hipMemsetAsync(cnt, 0, sizeof(unsigned), stream);

    vq_prep<<<1, 512, 0, stream>>>(w, w2, w2p3, whi, wmid);
    vq_gemm<<<NROWS / 512, 512, 0, stream>>>(x, whi, wmid, w2p3, out_idx, cnt, list, listcap);
    vq_recheck<<<256, 256, 0, stream>>>(x, w, w2, cnt, list, listcap, out_idx);
    vq_epilogue<<<NROWS / 256, 256, 0, stream>>>(x, w, out_idx, out_q, out_loss);
}

// Round 6
// 253.546 us; speedup vs baseline: 3.5710x; 3.5710x over previous
//
#include <hip/hip_runtime.h>

// VectorQuantizer: N=262144 rows, D=64 dims, K=512 codewords, fp32.
// out layout (floats): [0,N) idx ; [N, N+N*D) quantized_st ; [N+N*D] vq_loss
//
// CORRECTNESS MODEL (verified R2-R5, absmax 0): reference fp32 bit pattern is
//   d2 = fl(fl(x2 - fl(2*m)) + w2), x2/w2 numpy pairwise-8 order, m = sequential
//   FMA chain d ascending (BLAS), argmin strict < (first-min tie-break).
// Two-phase: MFMA approx scores (bf16 hi/mid splits of -2w, 3 terms, 6 chained
// mfma_16x16x32_bf16) + exact-chain recheck of rows with top-2 gap < margin.
#define NROWS 262144
#define DDIM  64
#define KCB   512

// key = (fp32 bits of s''=w2+3-2*dot) << 9 | cw ; s'' in [2.8,3.2] => one
// exponent octave => bits monotone. 1 key unit = ulp(3)/512 ; MARGKEY = 3<<17
// => 768 ulps = 1.83e-4 >= 2x worst-case |approx - ref| bound (~9.1e-5).
#define MARGKEY (3u << 17)

// ws layout (bytes)
#define WS_CNT   0
#define WS_W2P3  1024
#define WS_WHI   4096
#define WS_WMID  69632
#define WS_LIST  135168

typedef __attribute__((ext_vector_type(8))) short short8;
typedef __attribute__((ext_vector_type(4))) float floatx4;

__device__ __forceinline__ unsigned umin2(unsigned a, unsigned b) { return a < b ? a : b; }
__device__ __forceinline__ unsigned umax2(unsigned a, unsigned b) { return a > b ? a : b; }

// numpy FLOAT_pairwise_sum order for n=64 over terms fl(a[i]*a[i])  [R2-verified]
__device__ __forceinline__ float np_sumsq64(const float* a) {
    float r[8];
#pragma unroll
    for (int j = 0; j < 8; ++j) r[j] = __fmul_rn(a[j], a[j]);
#pragma unroll
    for (int i = 8; i < 64; i += 8) {
#pragma unroll
        for (int j = 0; j < 8; ++j)
            r[j] = __fadd_rn(r[j], __fmul_rn(a[i + j], a[i + j]));
    }
    return __fadd_rn(__fadd_rn(__fadd_rn(r[0], r[1]), __fadd_rn(r[2], r[3])),
                     __fadd_rn(__fadd_rn(r[4], r[5]), __fadd_rn(r[6], r[7])));
}

// pack two fp32 into bf16-truncate hi dword + residual-bf16 mid dword
__device__ __forceinline__ void split2(float e0, float e1, unsigned& hid, unsigned& mid) {
    unsigned u0 = __float_as_uint(e0), u1 = __float_as_uint(e1);
    float r0 = __fsub_rn(e0, __uint_as_float(u0 & 0xFFFF0000u));  // exact
    float r1 = __fsub_rn(e1, __uint_as_float(u1 & 0xFFFF0000u));  // exact
    hid = (u0 >> 16) | (u1 & 0xFFFF0000u);
    mid = (__float_as_uint(r0) >> 16) | (__float_as_uint(r1) & 0xFFFF0000u);
}

// ---- prep: w2p3 = fl(w2)+3, bf16 truncated splits of v = -2*w ----
__global__ void vq_prep(const float* __restrict__ w, float* __restrict__ w2p3,
                        unsigned short* __restrict__ whi,
                        unsigned short* __restrict__ wmid) {
    const int k = threadIdx.x;  // 512 threads, 1 block
    float ws[64];
    const float4* wp = (const float4*)(w + (size_t)k * DDIM);
#pragma unroll
    for (int j = 0; j < 16; ++j) {
        float4 v = wp[j];
        ws[4 * j + 0] = v.x; ws[4 * j + 1] = v.y;
        ws[4 * j + 2] = v.z; ws[4 * j + 3] = v.w;
    }
    w2p3[k] = __fadd_rn(np_sumsq64(ws), 3.0f);
#pragma unroll
    for (int d = 0; d < 64; ++d) {
        float v = __fmul_rn(-2.0f, ws[d]);           // exact (pow2 scale)
        unsigned u = __float_as_uint(v);
        whi[k * 64 + d] = (unsigned short)(u >> 16); // bf16 truncate
        float rem = __fsub_rn(v, __uint_as_float(u & 0xFFFF0000u));  // exact
        wmid[k * 64 + d] = (unsigned short)(__float_as_uint(rem) >> 16);
    }
}

// ---- phase-1: 512 thr = 8 waves; wave owns 64 codewords (A in regs);
// 16 rows/iter staged to double-buffered LDS; deferred cross-wave merge ----
__launch_bounds__(512, 4)
__global__ void vq_gemm(const float* __restrict__ x,
                        const unsigned short* __restrict__ whi,
                        const unsigned short* __restrict__ wmid,
                        const float* __restrict__ w2p3g,
                        float* __restrict__ out_idx,
                        unsigned* __restrict__ cnt,
                        unsigned* __restrict__ list, int listcap) {
    const int tid = threadIdx.x;
    const int wave = tid >> 6, lane = tid & 63;
    const int n16 = lane & 15, quad = lane >> 4;

    __shared__ float w2p3s[KCB];                         // 2 KB
    __shared__ __align__(16) unsigned sbh[2][16 * 36];   // B hi tiles, pad 36 dw/row
    __shared__ __align__(16) unsigned sbm[2][16 * 36];   // B mid tiles
    __shared__ uint2 mm[8][32][16];                      // per-wave min1/min2, 32 KB

    w2p3s[tid] = w2p3g[tid];

    // A-frags (R5-verified layout): A[m=lane&15][k=quad*8+j], 2 K-chunks
    short8 ah[4][2], am[4][2];
#pragma unroll
    for (int f = 0; f < 4; ++f) {
        const int cw = wave * 64 + f * 16 + n16;
#pragma unroll
        for (int s = 0; s < 2; ++s) {
            ah[f][s] = *(const short8*)(whi + (size_t)cw * 64 + s * 32 + quad * 8);
            am[f][s] = *(const short8*)(wmid + (size_t)cw * 64 + s * 32 + quad * 8);
        }
    }

    const int r0 = blockIdx.x * 512;
    const int srow = tid >> 5, sj2 = tid & 31;   // staging coords: row, dword
    // prologue: stage it=0 (coalesced float2 per thread)
    {
        float2 v = *(const float2*)(x + (size_t)(r0 + srow) * DDIM + 2 * sj2);
        unsigned hid, mid; split2(v.x, v.y, hid, mid);
        sbh[0][srow * 36 + sj2] = hid;
        sbm[0][srow * 36 + sj2] = mid;
    }
    __syncthreads();

    const unsigned cwq = (unsigned)(wave * 64 + quad * 4);

    for (int it = 0; it < 32; ++it) {
        const int p = it & 1;
        // prefetch next 16 rows (load issued before MFMA work; used at tail)
        float2 pre;
        if (it < 31)
            pre = *(const float2*)(x + (size_t)(r0 + (it + 1) * 16 + srow) * DDIM + 2 * sj2);

        // B-frags from LDS: row n16, dwords s*16 + quad*4 .. +3
        short8 b_h0 = *(const short8*)&sbh[p][n16 * 36 + quad * 4];
        short8 b_h1 = *(const short8*)&sbh[p][n16 * 36 + 16 + quad * 4];
        short8 b_m0 = *(const short8*)&sbm[p][n16 * 36 + quad * 4];
        short8 b_m1 = *(const short8*)&sbm[p][n16 * 36 + 16 + quad * 4];

        floatx4 acc[4];
#pragma unroll
        for (int f = 0; f < 4; ++f)
            acc[f] = *(const floatx4*)&w2p3s[wave * 64 + f * 16 + quad * 4];
#pragma unroll
        for (int f = 0; f < 4; ++f) {
            acc[f] = __builtin_amdgcn_mfma_f32_16x16x32_bf16(ah[f][0], b_h0, acc[f], 0, 0, 0);
            acc[f] = __builtin_amdgcn_mfma_f32_16x16x32_bf16(ah[f][0], b_m0, acc[f], 0, 0, 0);
            acc[f] = __builtin_amdgcn_mfma_f32_16x16x32_bf16(am[f][0], b_h0, acc[f], 0, 0, 0);
            acc[f] = __builtin_amdgcn_mfma_f32_16x16x32_bf16(ah[f][1], b_h1, acc[f], 0, 0, 0);
            acc[f] = __builtin_amdgcn_mfma_f32_16x16x32_bf16(ah[f][1], b_m1, acc[f], 0, 0, 0);
            acc[f] = __builtin_amdgcn_mfma_f32_16x16x32_bf16(am[f][1], b_h1, acc[f], 0, 0, 0);
        }

        // per-lane min1/min2 over this lane's 16 (cw,score) for row r0+it*16+n16
        unsigned m1 = 0xFFFFFFFFu, m2 = 0xFFFFFFFFu;
#pragma unroll
        for (int f = 0; f < 4; ++f) {
#pragma unroll
            for (int reg = 0; reg < 4; ++reg) {
                unsigned key = (__float_as_uint(acc[f][reg]) << 9) +
                               (cwq + (unsigned)(f * 16 + reg));
                unsigned t = umax2(m1, key);
                m2 = umin2(m2, t);
                m1 = umin2(m1, key);
            }
        }
        // merge across the 4 quads holding the same row
#pragma unroll
        for (int s = 16; s <= 32; s <<= 1) {
            unsigned o1 = __shfl_xor((int)m1, s);
            unsigned o2 = __shfl_xor((int)m2, s);
            m2 = umin2(umin2(m2, o2), umax2(m1, o1));
            m1 = umin2(m1, o1);
        }
        if (lane < 16) mm[wave][it][n16] = make_uint2(m1, m2);

        // stage it+1 into the other buffer (readers of it-1 finished at last barrier)
        if (it < 31) {
            unsigned hid, mid; split2(pre.x, pre.y, hid, mid);
            sbh[p ^ 1][srow * 36 + sj2] = hid;
            sbm[p ^ 1][srow * 36 + sj2] = mid;
        }
        __syncthreads();
    }

    // ---- deferred merge: thread tid owns row r0+tid (it=tid>>4, rl=tid&15) ----
    unsigned a1 = 0xFFFFFFFFu, a2 = 0xFFFFFFFFu;
#pragma unroll
    for (int wv = 0; wv < 8; ++wv) {
        uint2 v = mm[wv][tid >> 4][tid & 15];
        a2 = umin2(umin2(a2, v.y), umax2(a1, v.x));
        a1 = umin2(a1, v.x);
    }
    out_idx[r0 + tid] = (float)(a1 & 511u);
    bool flag = (a2 - a1 < MARGKEY);
    unsigned long long mask = __ballot(flag);
    int nw = __popcll(mask);
    unsigned base = 0;
    if (lane == 0 && nw) base = atomicAdd(cnt, (unsigned)nw);
    base = (unsigned)__shfl((int)base, 0);
    if (flag) {
        unsigned pos = base + (unsigned)__popcll(mask & ((1ull << lane) - 1ull));
        if ((int)pos < listcap) list[pos] = (unsigned)(r0 + tid);
    }
}

// ---- recheck: R4-verified structure (thread owns codeword, exact chains,
// LDS d2 tile + exact argmin), rows indirect via flag list ----
__launch_bounds__(512, 4)
__global__ void vq_recheck(const float* __restrict__ x,
                           const float* __restrict__ w,
                           const unsigned* __restrict__ cnt,
                           const unsigned* __restrict__ list, int listcap,
                           float* __restrict__ out_idx) {
    const int tid = threadIdx.x;
    unsigned total = *cnt;
    if (total > (unsigned)listcap) total = (unsigned)listcap;
    const unsigned nb = (total + 15) >> 4;

    // this thread's codeword + its exact w2 (numpy order)
    float wl[64];
    {
        const float4* wp = (const float4*)(w + (size_t)tid * DDIM);
#pragma unroll
        for (int j = 0; j < 16; ++j) {
            float4 v = wp[j];
            wl[4 * j + 0] = v.x; wl[4 * j + 1] = v.y;
            wl[4 * j + 2] = v.z; wl[4 * j + 3] = v.w;
        }
    }
    const float w2l = np_sumsq64(wl);

    __shared__ float d2tile[16][KCB];   // 32 KB
    __shared__ int rowbuf[16];
    __shared__ float x2buf[16];

    for (unsigned batch = blockIdx.x; batch < nb; batch += gridDim.x) {
        if (tid < 16) {
            unsigned li = batch * 16 + (unsigned)tid;
            rowbuf[tid] = (li < total) ? (int)list[li] : -1;
        }
        __syncthreads();

        // x2 per row: 8 threads/row, numpy pairwise-8 order + exact shfl tree
        if (tid < 128) {
            const int rl = tid >> 3, j = tid & 7;
            int row = rowbuf[rl]; if (row < 0) row = 0;
            const float* xr = x + (size_t)row * DDIM;
            float a0 = xr[j];
            float r = __fmul_rn(a0, a0);
#pragma unroll
            for (int i = 1; i < 8; ++i) {
                float ai = xr[8 * i + j];
                r = __fadd_rn(r, __fmul_rn(ai, ai));
            }
            float s1 = __fadd_rn(r,  __shfl_xor(r, 1));
            float s2 = __fadd_rn(s1, __shfl_xor(s1, 2));
            float s4 = __fadd_rn(s2, __shfl_xor(s2, 4));
            if (j == 0) x2buf[rl] = s4;
        }
        __syncthreads();

        // exact chains: 4 rows in flight, block-uniform broadcast x loads
        for (int g = 0; g < 16; g += 4) {
            int ra = rowbuf[g + 0]; if (ra < 0) ra = 0;
            int rb = rowbuf[g + 1]; if (rb < 0) rb = 0;
            int rc = rowbuf[g + 2]; if (rc < 0) rc = 0;
            int rd = rowbuf[g + 3]; if (rd < 0) rd = 0;
            const float* xr0 = x + (size_t)ra * DDIM;
            const float* xr1 = x + (size_t)rb * DDIM;
            const float* xr2 = x + (size_t)rc * DDIM;
            const float* xr3 = x + (size_t)rd * DDIM;
            float m0 = 0.f, m1 = 0.f, m2 = 0.f, m3 = 0.f;
#pragma unroll
            for (int jb = 0; jb < 16; ++jb) {
                float4 a0 = *(const float4*)(xr0 + 4 * jb);
                float4 a1 = *(const float4*)(xr1 + 4 * jb);
                float4 a2 = *(const float4*)(xr2 + 4 * jb);
                float4 a3 = *(const float4*)(xr3 + 4 * jb);
                m0 = __fmaf_rn(a0.x, wl[4 * jb + 0], m0);
                m0 = __fmaf_rn(a0.y, wl[4 * jb + 1], m0);
                m0 = __fmaf_rn(a0.z, wl[4 * jb + 2], m0);
                m0 = __fmaf_rn(a0.w, wl[4 * jb + 3], m0);
                m1 = __fmaf_rn(a1.x, wl[4 * jb + 0], m1);
                m1 = __fmaf_rn(a1.y, wl[4 * jb + 1], m1);
                m1 = __fmaf_rn(a1.z, wl[4 * jb + 2], m1);
                m1 = __fmaf_rn(a1.w, wl[4 * jb + 3], m1);
                m2 = __fmaf_rn(a2.x, wl[4 * jb + 0], m2);
                m2 = __fmaf_rn(a2.y, wl[4 * jb + 1], m2);
                m2 = __fmaf_rn(a2.z, wl[4 * jb + 2], m2);
                m2 = __fmaf_rn(a2.w, wl[4 * jb + 3], m2);
                m3 = __fmaf_rn(a3.x, wl[4 * jb + 0], m3);
                m3 = __fmaf_rn(a3.y, wl[4 * jb + 1], m3);
                m3 = __fmaf_rn(a3.z, wl[4 * jb + 2], m3);
                m3 = __fmaf_rn(a3.w, wl[4 * jb + 3], m3);
            }
            float X0 = x2buf[g + 0], X1 = x2buf[g + 1];
            float X2 = x2buf[g + 2], X3 = x2buf[g + 3];
            d2tile[g + 0][tid] = __fadd_rn(__fsub_rn(X0, __fmul_rn(2.0f, m0)), w2l);
            d2tile[g + 1][tid] = __fadd_rn(__fsub_rn(X1, __fmul_rn(2.0f, m1)), w2l);
            d2tile[g + 2][tid] = __fadd_rn(__fsub_rn(X2, __fmul_rn(2.0f, m2)), w2l);
            d2tile[g + 3][tid] = __fadd_rn(__fsub_rn(X3, __fmul_rn(2.0f, m3)), w2l);
        }
        __syncthreads();

        // exact argmin per row: 32 threads/row, strict < first-min [R4-verified]
        {
            const int rl  = tid >> 5;
            const int sub = tid & 31;
            float bv = d2tile[rl][sub];
            int   bi = sub;
#pragma unroll
            for (int i = 1; i < 16; ++i) {
                int cc = sub + 32 * i;
                float v = d2tile[rl][cc];
                if (v < bv) { bv = v; bi = cc; }
            }
#pragma unroll
            for (int s = 1; s < 32; s <<= 1) {
                float ov = __shfl_xor(bv, s);
                int   oi = __shfl_xor(bi, s);
                if (ov < bv || (ov == bv && oi < bi)) { bv = ov; bi = oi; }
            }
            if (sub == 0 && rowbuf[rl] >= 0) out_idx[rowbuf[rl]] = (float)bi;
        }
        __syncthreads();
    }
}

// ---- epilogue: gather codeword, quantized_st = fl(x + fl(q-x)), loss [R4-verified] ----
__launch_bounds__(256)
__global__ void vq_epilogue(const float* __restrict__ x,
                            const float* __restrict__ w,
                            const float* __restrict__ out_idx_f,
                            float* __restrict__ out_q,
                            float* __restrict__ out_loss) {
    const int row  = blockIdx.x * blockDim.x + threadIdx.x;
    const int bidx = (int)out_idx_f[row];

    const float4* xp = (const float4*)(x + (size_t)row * DDIM);
    const float4* wq = (const float4*)(w + (size_t)bidx * DDIM);
    float4* qo = (float4*)(out_q + (size_t)row * DDIM);
    float ls = 0.0f;
#pragma unroll
    for (int j = 0; j < 16; ++j) {
        float4 xv = xp[j];
        float4 wv = wq[j];
        float e0 = __fsub_rn(wv.x, xv.x), e1 = __fsub_rn(wv.y, xv.y);
        float e2 = __fsub_rn(wv.z, xv.z), e3 = __fsub_rn(wv.w, xv.w);
        ls = fmaf(e0, e0, ls); ls = fmaf(e1, e1, ls);
        ls = fmaf(e2, e2, ls); ls = fmaf(e3, e3, ls);
        float4 q;
        q.x = __fadd_rn(xv.x, e0); q.y = __fadd_rn(xv.y, e1);
        q.z = __fadd_rn(xv.z, e2); q.w = __fadd_rn(xv.w, e3);
        qo[j] = q;
    }
#pragma unroll
    for (int off = 32; off > 0; off >>= 1) ls += __shfl_down(ls, off);
    __shared__ float red[4];
    const int lane = threadIdx.x & 63;
    const int wid  = threadIdx.x >> 6;
    if (lane == 0) red[wid] = ls;
    __syncthreads();
    if (threadIdx.x == 0) {
        float t = (red[0] + red[1]) + (red[2] + red[3]);
        atomicAdd(out_loss, t * (1.25f / (float)(NROWS * DDIM)));  // (1+BETA)*mean
    }
}

extern "C" void kernel_launch(void* const* d_in, const int* in_sizes, int n_in,
                              void* d_out, int out_size, void* d_ws, size_t ws_size,
                              hipStream_t stream) {
    const float* x = (const float*)d_in[0];   // encoding [N, 64]
    const float* w = (const float*)d_in[1];   // weight   [512, 64]

    float* out      = (float*)d_out;
    float* out_idx  = out;
    float* out_q    = out + (size_t)NROWS;
    float* out_loss = out + (size_t)NROWS + (size_t)NROWS * DDIM;

    char* ws = (char*)d_ws;
    unsigned* cnt  = (unsigned*)(ws + WS_CNT);
    float* w2p3    = (float*)(ws + WS_W2P3);
    unsigned short* whi  = (unsigned short*)(ws + WS_WHI);
    unsigned short* wmid = (unsigned short*)(ws + WS_WMID);
    unsigned* list = (unsigned*)(ws + WS_LIST);
    long cap = ((long)ws_size - WS_LIST) / 4;
    int listcap = cap > 0 ? (cap > NROWS ? NROWS : (int)cap) : 0;

    hipMemsetAsync(out_loss, 0, sizeof(float), stream);
    hipMemsetAsync(cnt, 0, sizeof(unsigned), stream);

    vq_prep<<<1, 512, 0, stream>>>(w, w2p3, whi, wmid);
    vq_gemm<<<NROWS / 512, 512, 0, stream>>>(x, whi, wmid, w2p3, out_idx, cnt, list, listcap);
    vq_recheck<<<256, 512, 0, stream>>>(x, w, cnt, list, listcap, out_idx);
    vq_epilogue<<<NROWS / 256, 256, 0, stream>>>(x, w, out_idx, out_q, out_loss);
}